// Round 5
// baseline (74.958 us; speedup 1.0000x reference)
//
#include <hip/hip_runtime.h>

#define NB   4
#define KCH  4
#define PPB  4096          // downsampled points per batch (64x64)
#define QT   32            // q per block
#define BLK  256           // threads per block
#define PT   2             // p per thread (p-tile = 512)
#define NBLK 576           // triangle blocks per batch: sum_{pt=0..7}(128-16*pt)
#define NPART (NBLK * NB)  // 2304 partials

#if __has_builtin(__builtin_amdgcn_exp2f)
#define EXPFN(x) __builtin_amdgcn_exp2f(x)
#define FSCALE 1.2011224087864498f   /* sqrt(log2(e)) */
#else
#define EXPFN(x) __expf(x)
#define FSCALE 1.0f
#endif

// Record layout (SoA over 16384 global points, ws-resident):
//   RA[p] = (x, y, r, g)          float4
//   RH[p] = (b, h)                float2   h = -0.5*|f|^2 (log2 units)
//   RS[p] = (s0, s1, s2, s3)      float4
// feats pre-scaled by FSCALE so exp2 needs no extra multiply.

__global__ __launch_bounds__(256) void crf_prep(const float* __restrict__ images,
                                                const float* __restrict__ segs,
                                                float4* __restrict__ RA,
                                                float2* __restrict__ RH,
                                                float4* __restrict__ RS) {
    int gid = blockIdx.x * BLK + threadIdx.x;   // 0..16383
    int n = gid >> 12;
    int p = gid & (PPB - 1);
    int i = p >> 6;
    int j = p & 63;
    int off = 256 * i + 2 * j;                  // pixel (2i, 2j) in 128x128
    const float* img = images + (size_t)n * 3 * 16384;
    float x = (float)j * (FSCALE / 50.0f);      // SIGMA_XY*SCALE = 50
    float y = (float)i * (FSCALE / 50.0f);
    float r = img[off]         * (FSCALE / 15.0f);   // SIGMA_RGB = 15
    float g = img[16384 + off] * (FSCALE / 15.0f);
    float b = img[32768 + off] * (FSCALE / 15.0f);
    float h = -0.5f * (x * x + y * y + r * r + g * g + b * b);
    const float* sg = segs + (size_t)n * KCH * 16384;
    float s0, s1, s2, s3;
    {
        float2 u0 = *(const float2*)(sg + off);
        float2 u1 = *(const float2*)(sg + off + 128);
        s0 = 0.25f * ((u0.x + u0.y) + (u1.x + u1.y));
        u0 = *(const float2*)(sg + 16384 + off);
        u1 = *(const float2*)(sg + 16384 + off + 128);
        s1 = 0.25f * ((u0.x + u0.y) + (u1.x + u1.y));
        u0 = *(const float2*)(sg + 32768 + off);
        u1 = *(const float2*)(sg + 32768 + off + 128);
        s2 = 0.25f * ((u0.x + u0.y) + (u1.x + u1.y));
        u0 = *(const float2*)(sg + 49152 + off);
        u1 = *(const float2*)(sg + 49152 + off + 128);
        s3 = 0.25f * ((u0.x + u0.y) + (u1.x + u1.y));
    }
    RA[gid] = make_float4(x, y, r, g);
    RH[gid] = make_float2(b, h);
    RS[gid] = make_float4(s0, s1, s2, s3);
}

// Pair kernel: asum formulation -- inner loop accumulates asum += w*Sq
// (4 independent FMAs after exp); the Sp dot is a per-block epilogue.
// PT=2, QT=32, 2304 blocks, __launch_bounds__(256,8) keeps 8 waves/SIMD.
// grid = (576 triangle blocks, 4 batches).
__global__ __launch_bounds__(256, 8) void crf_pairs(const float4* __restrict__ RA,
                                                    const float2* __restrict__ RH,
                                                    const float4* __restrict__ RS,
                                                    float* __restrict__ part) {
    __shared__ float4 ldsA[QT];
    __shared__ float2 ldsH[QT];
    __shared__ float4 ldsS[QT];
    __shared__ float wsum[BLK / 64];

    int t = threadIdx.x;
    int n = blockIdx.y;

    // Decode triangle block index -> (p-tile pt of 512, q-chunk qc of 32),
    // qc >= 16*pt. counts per pt: 128-16*pt ; cum(pt) = 8*pt*(17-pt)
    int b = blockIdx.x;                  // 0..575
    int pt = 0;
#pragma unroll
    for (int i = 1; i < 8; ++i) pt += (b >= 8 * i * (17 - i)) ? 1 : 0;
    int qc = b - 8 * pt * (17 - pt) + 16 * pt;
    int pbase = pt * (BLK * PT);         // pt*512
    int qbase = qc * QT;
    bool mixed = (qc >> 4) == pt;        // q-chunk inside the p-tile
    int base = n << 12;

    // Stage q-records into LDS (one-time).
    if (t < QT)            ldsA[t]          = RA[base + qbase + t];
    else if (t < 2 * QT)   ldsH[t - QT]     = RH[base + qbase + (t - QT)];
    else if (t < 3 * QT)   ldsS[t - 2 * QT] = RS[base + qbase + (t - 2 * QT)];

    // p-records: feats only; seg values are loaded in the epilogue.
    float4 pa0 = RA[base + pbase + t];
    float4 pa1 = RA[base + pbase + t + BLK];
    float2 ph0 = RH[base + pbase + t];
    float2 ph1 = RH[base + pbase + t + BLK];
    __syncthreads();

    float4 as0 = make_float4(0.f, 0.f, 0.f, 0.f);
    float4 as1 = make_float4(0.f, 0.f, 0.f, 0.f);

    if (!mixed) {
        // Strictly above the diagonal: every pair counts twice (folded later).
#pragma unroll
        for (int q = 0; q < QT; ++q) {
            float4 fa = ldsA[q];
            float2 fh = ldsH[q];
            float4 fs = ldsS[q];

            float d0 = ph0.y + fh.y;
            d0 = fmaf(pa0.x, fa.x, d0);
            d0 = fmaf(pa0.y, fa.y, d0);
            d0 = fmaf(pa0.z, fa.z, d0);
            d0 = fmaf(pa0.w, fa.w, d0);
            d0 = fmaf(ph0.x, fh.x, d0);
            float w0 = EXPFN(d0);
            as0.x = fmaf(w0, fs.x, as0.x);
            as0.y = fmaf(w0, fs.y, as0.y);
            as0.z = fmaf(w0, fs.z, as0.z);
            as0.w = fmaf(w0, fs.w, as0.w);

            float d1 = ph1.y + fh.y;
            d1 = fmaf(pa1.x, fa.x, d1);
            d1 = fmaf(pa1.y, fa.y, d1);
            d1 = fmaf(pa1.z, fa.z, d1);
            d1 = fmaf(pa1.w, fa.w, d1);
            d1 = fmaf(ph1.x, fh.x, d1);
            float w1 = EXPFN(d1);
            as1.x = fmaf(w1, fs.x, as1.x);
            as1.y = fmaf(w1, fs.y, as1.y);
            as1.z = fmaf(w1, fs.z, as1.z);
            as1.w = fmaf(w1, fs.w, as1.w);
        }
    } else {
        // Diagonal-overlap block: weight pairs 2/1/0 for q>p / q==p / q<p,
        // folded into w before the asum FMAs. (8 of 576 blocks.)
        int pg0 = pbase + t;
        int pg1 = pbase + t + BLK;
#pragma unroll
        for (int q = 0; q < QT; ++q) {
            float4 fa = ldsA[q];
            float2 fh = ldsH[q];
            float4 fs = ldsS[q];
            int qg = qbase + q;

            float d0 = ph0.y + fh.y;
            d0 = fmaf(pa0.x, fa.x, d0);
            d0 = fmaf(pa0.y, fa.y, d0);
            d0 = fmaf(pa0.z, fa.z, d0);
            d0 = fmaf(pa0.w, fa.w, d0);
            d0 = fmaf(ph0.x, fh.x, d0);
            float f0 = (qg > pg0) ? 2.0f : ((qg == pg0) ? 1.0f : 0.0f);
            float w0 = EXPFN(d0) * f0;
            as0.x = fmaf(w0, fs.x, as0.x);
            as0.y = fmaf(w0, fs.y, as0.y);
            as0.z = fmaf(w0, fs.z, as0.z);
            as0.w = fmaf(w0, fs.w, as0.w);

            float d1 = ph1.y + fh.y;
            d1 = fmaf(pa1.x, fa.x, d1);
            d1 = fmaf(pa1.y, fa.y, d1);
            d1 = fmaf(pa1.z, fa.z, d1);
            d1 = fmaf(pa1.w, fa.w, d1);
            d1 = fmaf(ph1.x, fh.x, d1);
            float f1 = (qg > pg1) ? 2.0f : ((qg == pg1) ? 1.0f : 0.0f);
            float w1 = EXPFN(d1) * f1;
            as1.x = fmaf(w1, fs.x, as1.x);
            as1.y = fmaf(w1, fs.y, as1.y);
            as1.z = fmaf(w1, fs.z, as1.z);
            as1.w = fmaf(w1, fs.w, as1.w);
        }
    }

    // Epilogue: dot with the p-side seg vectors (loaded only now).
    float4 ps0 = RS[base + pbase + t];
    float4 ps1 = RS[base + pbase + t + BLK];
    float t0 = as0.x * ps0.x;
    t0 = fmaf(as0.y, ps0.y, t0);
    t0 = fmaf(as0.z, ps0.z, t0);
    t0 = fmaf(as0.w, ps0.w, t0);
    float t1 = as1.x * ps1.x;
    t1 = fmaf(as1.y, ps1.y, t1);
    t1 = fmaf(as1.z, ps1.z, t1);
    t1 = fmaf(as1.w, ps1.w, t1);
    float acc_all = mixed ? (t0 + t1) : 2.0f * (t0 + t1);

#pragma unroll
    for (int off = 32; off > 0; off >>= 1)
        acc_all += __shfl_down(acc_all, off, 64);
    if ((t & 63) == 0) wsum[t >> 6] = acc_all;
    __syncthreads();
    if (t == 0) {
        part[n * NBLK + blockIdx.x] =
            (wsum[0] + wsum[1]) + (wsum[2] + wsum[3]);
    }
}

// Final reduction: 2304 partials -> out[0], single block, no atomics.
__global__ __launch_bounds__(256) void crf_reduce(const float* __restrict__ part,
                                                  float* __restrict__ out) {
    __shared__ float wsum[BLK / 64];
    int t = threadIdx.x;
    float s = 0.f;
#pragma unroll
    for (int i = 0; i < NPART / BLK; ++i)       // 9 iterations, exact
        s += part[t + i * BLK];
#pragma unroll
    for (int off = 32; off > 0; off >>= 1)
        s += __shfl_down(s, off, 64);
    if ((t & 63) == 0) wsum[t >> 6] = s;
    __syncthreads();
    if (t == 0) {
        float tot = (wsum[0] + wsum[1]) + (wsum[2] + wsum[3]);
        // loss = WEIGHT * (-sum / n) = -1e-7/4 * sum
        out[0] = tot * (-2.5e-8f);
    }
}

extern "C" void kernel_launch(void* const* d_in, const int* in_sizes, int n_in,
                              void* d_out, int out_size, void* d_ws, size_t ws_size,
                              hipStream_t stream) {
    const float* images = (const float*)d_in[0];
    const float* segs   = (const float*)d_in[1];
    float* out = (float*)d_out;
    char* ws = (char*)d_ws;
    float4* RA = (float4*)(ws);                 // 16384 * 16 B = 256 KiB
    float2* RH = (float2*)(ws + 262144);        // 128 KiB
    float4* RS = (float4*)(ws + 393216);        // 256 KiB
    float* part = (float*)(ws + 655360);        // 2304 * 4 B
    (void)in_sizes; (void)n_in; (void)out_size; (void)ws_size;

    crf_prep<<<dim3(64), dim3(256), 0, stream>>>(images, segs, RA, RH, RS);
    crf_pairs<<<dim3(NBLK, NB), dim3(256), 0, stream>>>(RA, RH, RS, part);
    crf_reduce<<<dim3(1), dim3(256), 0, stream>>>(part, out);
}